// Round 7
// baseline (226.908 us; speedup 1.0000x reference)
//
#include <hip/hip_runtime.h>
#include <math.h>

typedef int intx4 __attribute__((ext_vector_type(4)));
typedef int intx8 __attribute__((ext_vector_type(8)));
typedef float floatx16 __attribute__((ext_vector_type(16)));

#define N_ROWS 8192
#define KDIM 1024

// E8M0 scale bytes: 123 -> 2^-4 per side (data pre-scaled by 2^4 each side)
#define SCALE_WORD 0x7B7B7B7B

// order-preserving float->int encoding for atomicMax
__device__ __forceinline__ int fenc(float f) {
  int i = __float_as_int(f);
  return i >= 0 ? i : (i ^ 0x7fffffff);
}
__device__ __forceinline__ float fdec(int e) {
  int b = e >= 0 ? e : (e ^ 0x7fffffff);
  return __int_as_float(b);
}

// Fused: one block per row of ex (b < 8192) or ey (b >= 8192).
// Computes 1/||x|| (fp32), writes row normalized*16 as e4m3 via HW cvt,
// inits the max slot.
__global__ __launch_bounds__(256) void normalize_kernel(
    const float* __restrict__ ex, const float* __restrict__ ey,
    unsigned char* __restrict__ exn, unsigned char* __restrict__ eyn,
    int* __restrict__ rowmax, int* __restrict__ colmax) {
  const int b = blockIdx.x;
  const int tid = threadIdx.x;
  const float* x;
  unsigned char* out;
  int* mslot;
  int row;
  if (b < N_ROWS) {
    x = ex; out = exn; mslot = rowmax; row = b;
  } else {
    x = ey; out = eyn; mslot = colmax; row = b - N_ROWS;
  }
  const float4* xr = (const float4*)(x + (size_t)row * KDIM);
  float4 v = xr[tid];  // 256 threads * 4 = 1024 elements
  float ss = v.x * v.x + v.y * v.y + v.z * v.z + v.w * v.w;
#pragma unroll
  for (int off = 32; off > 0; off >>= 1) ss += __shfl_down(ss, off, 64);
  __shared__ float sred[4];
  if ((tid & 63) == 0) sred[tid >> 6] = ss;
  __syncthreads();
  const float total = sred[0] + sred[1] + sred[2] + sred[3];
  const float rs = 16.0f * rsqrtf(fmaxf(total, 1e-24f));  // 2^4 pre-scale
  // gfx950 HW fp8 (OCP e4m3fn) pack: two f32 -> low/high half-word
  int w = __builtin_amdgcn_cvt_pk_fp8_f32(v.x * rs, v.y * rs, 0, false);
  w = __builtin_amdgcn_cvt_pk_fp8_f32(v.z * rs, v.w * rs, w, true);
  ((int*)(out + (size_t)row * KDIM))[tid] = w;
  if (tid == 0) mslot[row] = (int)0x80000000;  // encoded -inf floor
}

// 128x128 tile GEMM (A @ B^T, row-major K-contiguous e4m3) using MX-scaled
// mfma_scale_f32_32x32x64_f8f6f4, fused with row/col max reduction.
//
// Round-7 change: BK 128 -> 64 with the 32x32x64 MFMA. Identical FLOP and
// LDS traffic, but per-block LDS drops 64 KB -> 32 KB so 3+ blocks/CU are
// resident (round 6 was LDS-capped at 2, latency-bound: no pipe >62% busy).
//
// Pipeline (round 6's verified shape): buffer_load->VGPR->ds_write; the only
// vmcnt wait is the ds_write's data dependence, placed AFTER compute:
//   LOAD(s+1); COMPUTE(buf s&1); WRITE(buf (s+1)&1); barrier
//
// LDS layout: row = 64 B = 4 chunks of 16 B; chunk c of row r at slot
// c ^ (r&3) (banks spread over all 32; staging source chunk picked per lane
// so the linear lane*16 ds_write dest matches — same scheme verified r3-r6).
// Operand mapping: lane (l32=lane&31, h=lane>>5) reads row l32's bytes
// h*32..h*32+31 for both A and B — the (h,j)->global-k map is identical for
// A and B, which is all dot-product pairing requires; uniform scales make
// MX 32-block boundaries irrelevant.
__global__ __launch_bounds__(256) void gemm_max_kernel(
    const unsigned char* __restrict__ A, const unsigned char* __restrict__ B,
    int* __restrict__ rowmax, int* __restrict__ colmax) {
  constexpr int TM = 128, BK = 64, K = KDIM;
  constexpr int BUF = TM * BK;                          // 8 KB per buffer
  __shared__ __align__(16) unsigned char sA[2 * BUF];   // 16 KB
  __shared__ __align__(16) unsigned char sB[2 * BUF];   // 16 KB

  const int bm = blockIdx.x, bn = blockIdx.y;
  const int tid = threadIdx.x;
  const int lane = tid & 63, wave = tid >> 6;
  const int wm = wave >> 1, wn = wave & 1;  // 2x2 waves of 64x64
  const int l32 = lane & 31, half = lane >> 5;
  const int oLo = (((2 * half + 0) ^ (l32 & 3)) << 4);  // swizzled slot offsets
  const int oHi = (((2 * half + 1) ^ (l32 & 3)) << 4);

  const char* Ab = (const char*)(A + (size_t)bm * TM * K);
  const char* Bb = (const char*)(B + (size_t)bn * TM * K);

  floatx16 acc[2][2] = {};

  // Staging: wave w stages rows w*32..w*32+31 of each tile per step.
  // One 16B/lane load covers 16 rows (4 chunk-lanes per row); 2 per matrix.
  const int r0 = wave * 32 + (lane >> 2);                 // lane's row (it=0)
  const int src_c16 = (((lane & 3) ^ ((lane >> 2) & 3)) << 4);
  const char* gA = Ab + (size_t)r0 * K + src_c16;
  const char* gB = Bb + (size_t)r0 * K + src_c16;
  unsigned char* wA = sA + wave * 2048 + lane * 16;  // linear dest (+buf,+it*1024)
  unsigned char* wB = sB + wave * 2048 + lane * 16;

  intx4 pf[4];  // prefetch regs: 2 A-chunks + 2 B-chunks (16 VGPRs)

#define LOADT(k0)                                            \
  do {                                                       \
    pf[0] = *(const intx4*)(gA + (size_t)(k0));              \
    pf[1] = *(const intx4*)(gA + (size_t)(k0) + 16 * K);     \
    pf[2] = *(const intx4*)(gB + (size_t)(k0));              \
    pf[3] = *(const intx4*)(gB + (size_t)(k0) + 16 * K);     \
  } while (0)

#define WRITET(buf)                                          \
  do {                                                       \
    *(intx4*)(wA + (buf)*BUF) = pf[0];                       \
    *(intx4*)(wA + (buf)*BUF + 1024) = pf[1];                \
    *(intx4*)(wB + (buf)*BUF) = pf[2];                       \
    *(intx4*)(wB + (buf)*BUF + 1024) = pf[3];                \
  } while (0)

#define COMPUTE(cur)                                                        \
  do {                                                                      \
    intx8 aF[2], bF[2];                                                     \
    _Pragma("unroll") for (int mi = 0; mi < 2; ++mi) {                      \
      const unsigned char* aBase =                                          \
          &sA[(cur)*BUF + (wm * 64 + mi * 32 + l32) * BK];                  \
      const intx4 lo = *(const intx4*)(aBase + oLo);                        \
      const intx4 hi = *(const intx4*)(aBase + oHi);                        \
      aF[mi] = __builtin_shufflevector(lo, hi, 0, 1, 2, 3, 4, 5, 6, 7);     \
    }                                                                       \
    _Pragma("unroll") for (int ni = 0; ni < 2; ++ni) {                      \
      const unsigned char* bBase =                                          \
          &sB[(cur)*BUF + (wn * 64 + ni * 32 + l32) * BK];                  \
      const intx4 lo = *(const intx4*)(bBase + oLo);                        \
      const intx4 hi = *(const intx4*)(bBase + oHi);                        \
      bF[ni] = __builtin_shufflevector(lo, hi, 0, 1, 2, 3, 4, 5, 6, 7);     \
    }                                                                       \
    _Pragma("unroll") for (int mi = 0; mi < 2; ++mi)                        \
        _Pragma("unroll") for (int ni = 0; ni < 2; ++ni)                    \
            acc[mi][ni] = __builtin_amdgcn_mfma_scale_f32_32x32x64_f8f6f4(  \
                aF[mi], bF[ni], acc[mi][ni], 0, 0, 0, SCALE_WORD, 0,        \
                SCALE_WORD);                                                \
  } while (0)

  LOADT(0);
  WRITET(0);
  __syncthreads();

  // unroll 1: keeps one pf set live (full unroll would hoist all 16 -> spill)
#pragma unroll 1
  for (int step = 0; step < K / BK - 1; ++step) {
    LOADT((step + 1) * BK);   // in flight across the whole compute phase
    COMPUTE(step & 1);
    WRITET((step + 1) & 1);   // vmcnt wait here is data-dependent, post-compute
    __syncthreads();
  }
  COMPUTE((K / BK - 1) & 1);

#undef LOADT
#undef WRITET
#undef COMPUTE

  // 32x32 C/D layout (m74/m101, dtype-independent):
  //   col = lane&31, row = (reg&3) + 8*(reg>>2) + 4*(lane>>5), reg in [0,16)
  // Row maxes: max over ni in-lane, then across the 32 cols (masks 1..16
  // preserve lane>>5). Lanes with l32==0 (one per half) write.
#pragma unroll
  for (int mi = 0; mi < 2; ++mi) {
#pragma unroll
    for (int reg = 0; reg < 16; ++reg) {
      float v = fmaxf(acc[mi][0][reg], acc[mi][1][reg]);
#pragma unroll
      for (int m = 1; m < 32; m <<= 1) v = fmaxf(v, __shfl_xor(v, m, 64));
      if (l32 == 0) {
        const int grow = bm * TM + wm * 64 + mi * 32 +
                         (reg & 3) + 8 * (reg >> 2) + 4 * half;
        atomicMax(&rowmax[grow], fenc(v));
      }
    }
  }
  // Col maxes: in-lane over mi,reg (32 vals), then combine the two halves
  // (lane ^ 32 has the same col, different rows).
#pragma unroll
  for (int ni = 0; ni < 2; ++ni) {
    float v = -3.402823466e38f;
#pragma unroll
    for (int mi = 0; mi < 2; ++mi)
#pragma unroll
      for (int reg = 0; reg < 16; ++reg) v = fmaxf(v, acc[mi][ni][reg]);
    v = fmaxf(v, __shfl_xor(v, 32, 64));
    if (half == 0) {
      const int gcol = bn * TM + wn * 64 + ni * 32 + l32;
      atomicMax(&colmax[gcol], fenc(v));
    }
  }
}

__global__ __launch_bounds__(1024) void finalize_kernel(
    const int* __restrict__ rowmax, const int* __restrict__ colmax,
    float* __restrict__ out) {
  const int tid = threadIdx.x;
  float s1 = 0.f, s2 = 0.f;
  for (int i = tid; i < N_ROWS; i += 1024) {
    s1 += 1.0f - fdec(rowmax[i]);
    s2 += 1.0f - fdec(colmax[i]);
  }
#pragma unroll
  for (int off = 32; off > 0; off >>= 1) {
    s1 += __shfl_down(s1, off, 64);
    s2 += __shfl_down(s2, off, 64);
  }
  __shared__ float r1[16], r2[16];
  if ((tid & 63) == 0) {
    r1[tid >> 6] = s1;
    r2[tid >> 6] = s2;
  }
  __syncthreads();
  if (tid == 0) {
    const double SIGMA = 0.3;
    const double H_CONST = 0.5 * log(2.0 * 3.14159265358979323846 * SIGMA * SIGMA) + 0.5;
    const float HS = (float)(H_CONST / SIGMA);
    float a1 = 0.f, a2 = 0.f;
#pragma unroll
    for (int w = 0; w < 16; ++w) {
      a1 += r1[w];
      a2 += r2[w];
    }
    out[0] = HS * a1;
    out[1] = HS * a2;
  }
}

extern "C" void kernel_launch(void* const* d_in, const int* in_sizes, int n_in,
                              void* d_out, int out_size, void* d_ws, size_t ws_size,
                              hipStream_t stream) {
  const float* ex = (const float*)d_in[0];
  const float* ey = (const float*)d_in[1];
  float* out = (float*)d_out;
  char* ws = (char*)d_ws;

  unsigned char* exn = (unsigned char*)ws;                                   // 8 MB
  unsigned char* eyn = (unsigned char*)(ws + (size_t)N_ROWS * KDIM);         // 8 MB
  int* rowmax = (int*)(ws + (size_t)N_ROWS * KDIM * 2);                      // 32 KB
  int* colmax = rowmax + N_ROWS;                                             // 32 KB

  normalize_kernel<<<2 * N_ROWS, 256, 0, stream>>>(ex, ey, exn, eyn, rowmax, colmax);
  gemm_max_kernel<<<dim3(64, 64), 256, 0, stream>>>(exn, eyn, rowmax, colmax);
  finalize_kernel<<<1, 1024, 0, stream>>>(rowmax, colmax, out);
}

// Round 8
// 216.201 us; speedup vs baseline: 1.0495x; 1.0495x over previous
//
#include <hip/hip_runtime.h>
#include <math.h>

typedef int intx4 __attribute__((ext_vector_type(4)));
typedef int intx8 __attribute__((ext_vector_type(8)));
typedef float floatx16 __attribute__((ext_vector_type(16)));

#define N_ROWS 8192
#define KDIM 1024

// E8M0 scale bytes: 123 -> 2^-4 per side (data pre-scaled by 2^4 each side)
#define SCALE_WORD 0x7B7B7B7B

// order-preserving float->int encoding for atomicMax
__device__ __forceinline__ int fenc(float f) {
  int i = __float_as_int(f);
  return i >= 0 ? i : (i ^ 0x7fffffff);
}
__device__ __forceinline__ float fdec(int e) {
  int b = e >= 0 ? e : (e ^ 0x7fffffff);
  return __int_as_float(b);
}

// Fused: one block per row of ex (b < 8192) or ey (b >= 8192).
// Computes 1/||x|| (fp32), writes row normalized*16 as e4m3 via HW cvt,
// inits the max slot.
__global__ __launch_bounds__(256) void normalize_kernel(
    const float* __restrict__ ex, const float* __restrict__ ey,
    unsigned char* __restrict__ exn, unsigned char* __restrict__ eyn,
    int* __restrict__ rowmax, int* __restrict__ colmax) {
  const int b = blockIdx.x;
  const int tid = threadIdx.x;
  const float* x;
  unsigned char* out;
  int* mslot;
  int row;
  if (b < N_ROWS) {
    x = ex; out = exn; mslot = rowmax; row = b;
  } else {
    x = ey; out = eyn; mslot = colmax; row = b - N_ROWS;
  }
  const float4* xr = (const float4*)(x + (size_t)row * KDIM);
  float4 v = xr[tid];  // 256 threads * 4 = 1024 elements
  float ss = v.x * v.x + v.y * v.y + v.z * v.z + v.w * v.w;
#pragma unroll
  for (int off = 32; off > 0; off >>= 1) ss += __shfl_down(ss, off, 64);
  __shared__ float sred[4];
  if ((tid & 63) == 0) sred[tid >> 6] = ss;
  __syncthreads();
  const float total = sred[0] + sred[1] + sred[2] + sred[3];
  const float rs = 16.0f * rsqrtf(fmaxf(total, 1e-24f));  // 2^4 pre-scale
  // gfx950 HW fp8 (OCP e4m3fn) pack: two f32 -> low/high half-word
  int w = __builtin_amdgcn_cvt_pk_fp8_f32(v.x * rs, v.y * rs, 0, false);
  w = __builtin_amdgcn_cvt_pk_fp8_f32(v.z * rs, v.w * rs, w, true);
  ((int*)(out + (size_t)row * KDIM))[tid] = w;
  if (tid == 0) mslot[row] = (int)0x80000000;  // encoded -inf floor
}

// 128x128 tile GEMM (A @ B^T, row-major K-contiguous e4m3) using MX-scaled
// mfma_scale_f32_32x32x64_f8f6f4, fused with row/col max reduction.
//
// Round-8 change: FIX the BK=64 bank swizzle. With 64-B row stride, a
// chunk's bank-group = 4*(r&1) + slot. Round 7 used slot = c ^ (l32&3),
// which collapses each quarter-wave onto 4 of 8 bank groups (16 lanes/group,
// 3x conflicts, the r7 regression). Now slot = c ^ ((r>>1)&3): bank-group
// = 4*(r&1) + (c^((r>>1)&3)) — every 16 consecutive lanes enumerate all 8
// groups x 2 lanes (2-way aliasing is free, m136).
//
// Pipeline (round 6's verified shape): buffer_load->VGPR->ds_write; the only
// vmcnt wait is the ds_write's data dependence, placed AFTER compute:
//   LOAD(s+1); COMPUTE(buf s&1); WRITE(buf (s+1)&1); barrier
//
// Operand mapping: lane (l32, h) reads row l32's bytes h*32..h*32+31 for
// both A and B — identical (h,j)->global-k map for A and B, all that
// dot-product pairing requires; uniform scales make MX 32-block boundaries
// irrelevant. Verified correct r3-r7 (absmax 0.0).
__global__ __launch_bounds__(256) void gemm_max_kernel(
    const unsigned char* __restrict__ A, const unsigned char* __restrict__ B,
    int* __restrict__ rowmax, int* __restrict__ colmax) {
  constexpr int TM = 128, BK = 64, K = KDIM;
  constexpr int BUF = TM * BK;                          // 8 KB per buffer
  __shared__ __align__(16) unsigned char sA[2 * BUF];   // 16 KB
  __shared__ __align__(16) unsigned char sB[2 * BUF];   // 16 KB

  const int bm = blockIdx.x, bn = blockIdx.y;
  const int tid = threadIdx.x;
  const int lane = tid & 63, wave = tid >> 6;
  const int wm = wave >> 1, wn = wave & 1;  // 2x2 waves of 64x64
  const int l32 = lane & 31, half = lane >> 5;
  const int fsw = (l32 >> 1) & 3;                    // f(row)= (row>>1)&3
  const int oLo = (((2 * half + 0) ^ fsw) << 4);     // swizzled slot offsets
  const int oHi = (((2 * half + 1) ^ fsw) << 4);

  const char* Ab = (const char*)(A + (size_t)bm * TM * K);
  const char* Bb = (const char*)(B + (size_t)bn * TM * K);

  floatx16 acc[2][2] = {};

  // Staging: wave w stages rows w*32..w*32+31 of each tile per step.
  // One 16B/lane load covers 16 rows (4 chunk-lanes per row); 2 per matrix.
  // Dest (linear lane*16): row r_d = wave*32 + (lane>>2), slot lane&3.
  // Source chunk = (lane&3) ^ f(r_d) = (lane&3) ^ ((lane>>3)&3); the +16-row
  // second write keeps the same offset (f(r+16)==f(r)).
  const int src_c16 = (((lane & 3) ^ ((lane >> 3) & 3)) << 4);
  const char* gA = Ab + (size_t)(wave * 32 + (lane >> 2)) * K + src_c16;
  const char* gB = Bb + (size_t)(wave * 32 + (lane >> 2)) * K + src_c16;
  unsigned char* wA = sA + wave * 2048 + lane * 16;  // linear dest (+buf,+it*1024)
  unsigned char* wB = sB + wave * 2048 + lane * 16;

  intx4 pf[4];  // prefetch regs: 2 A-chunks + 2 B-chunks (16 VGPRs)

#define LOADT(k0)                                            \
  do {                                                       \
    pf[0] = *(const intx4*)(gA + (size_t)(k0));              \
    pf[1] = *(const intx4*)(gA + (size_t)(k0) + 16 * K);     \
    pf[2] = *(const intx4*)(gB + (size_t)(k0));              \
    pf[3] = *(const intx4*)(gB + (size_t)(k0) + 16 * K);     \
  } while (0)

#define WRITET(buf)                                          \
  do {                                                       \
    *(intx4*)(wA + (buf)*BUF) = pf[0];                       \
    *(intx4*)(wA + (buf)*BUF + 1024) = pf[1];                \
    *(intx4*)(wB + (buf)*BUF) = pf[2];                       \
    *(intx4*)(wB + (buf)*BUF + 1024) = pf[3];                \
  } while (0)

#define COMPUTE(cur)                                                        \
  do {                                                                      \
    intx8 aF[2], bF[2];                                                     \
    _Pragma("unroll") for (int mi = 0; mi < 2; ++mi) {                      \
      const unsigned char* aBase =                                          \
          &sA[(cur)*BUF + (wm * 64 + mi * 32 + l32) * BK];                  \
      const intx4 lo = *(const intx4*)(aBase + oLo);                        \
      const intx4 hi = *(const intx4*)(aBase + oHi);                        \
      aF[mi] = __builtin_shufflevector(lo, hi, 0, 1, 2, 3, 4, 5, 6, 7);     \
    }                                                                       \
    _Pragma("unroll") for (int ni = 0; ni < 2; ++ni) {                      \
      const unsigned char* bBase =                                          \
          &sB[(cur)*BUF + (wn * 64 + ni * 32 + l32) * BK];                  \
      const intx4 lo = *(const intx4*)(bBase + oLo);                        \
      const intx4 hi = *(const intx4*)(bBase + oHi);                        \
      bF[ni] = __builtin_shufflevector(lo, hi, 0, 1, 2, 3, 4, 5, 6, 7);     \
    }                                                                       \
    _Pragma("unroll") for (int mi = 0; mi < 2; ++mi)                        \
        _Pragma("unroll") for (int ni = 0; ni < 2; ++ni)                    \
            acc[mi][ni] = __builtin_amdgcn_mfma_scale_f32_32x32x64_f8f6f4(  \
                aF[mi], bF[ni], acc[mi][ni], 0, 0, 0, SCALE_WORD, 0,        \
                SCALE_WORD);                                                \
  } while (0)

  LOADT(0);
  WRITET(0);
  __syncthreads();

  // unroll 1: keeps one pf set live (full unroll would hoist all 16 -> spill)
#pragma unroll 1
  for (int step = 0; step < K / BK - 1; ++step) {
    LOADT((step + 1) * BK);   // in flight across the whole compute phase
    COMPUTE(step & 1);
    WRITET((step + 1) & 1);   // vmcnt wait here is data-dependent, post-compute
    __syncthreads();
  }
  COMPUTE((K / BK - 1) & 1);

#undef LOADT
#undef WRITET
#undef COMPUTE

  // 32x32 C/D layout (m74/m101, dtype-independent):
  //   col = lane&31, row = (reg&3) + 8*(reg>>2) + 4*(lane>>5), reg in [0,16)
  // Row maxes: max over ni in-lane, then across the 32 cols (masks 1..16
  // preserve lane>>5). Lanes with l32==0 (one per half) write.
#pragma unroll
  for (int mi = 0; mi < 2; ++mi) {
#pragma unroll
    for (int reg = 0; reg < 16; ++reg) {
      float v = fmaxf(acc[mi][0][reg], acc[mi][1][reg]);
#pragma unroll
      for (int m = 1; m < 32; m <<= 1) v = fmaxf(v, __shfl_xor(v, m, 64));
      if (l32 == 0) {
        const int grow = bm * TM + wm * 64 + mi * 32 +
                         (reg & 3) + 8 * (reg >> 2) + 4 * half;
        atomicMax(&rowmax[grow], fenc(v));
      }
    }
  }
  // Col maxes: in-lane over mi,reg (32 vals), then combine the two halves
  // (lane ^ 32 has the same col, different rows).
#pragma unroll
  for (int ni = 0; ni < 2; ++ni) {
    float v = -3.402823466e38f;
#pragma unroll
    for (int mi = 0; mi < 2; ++mi)
#pragma unroll
      for (int reg = 0; reg < 16; ++reg) v = fmaxf(v, acc[mi][ni][reg]);
    v = fmaxf(v, __shfl_xor(v, 32, 64));
    if (half == 0) {
      const int gcol = bn * TM + wn * 64 + ni * 32 + l32;
      atomicMax(&colmax[gcol], fenc(v));
    }
  }
}

__global__ __launch_bounds__(1024) void finalize_kernel(
    const int* __restrict__ rowmax, const int* __restrict__ colmax,
    float* __restrict__ out) {
  const int tid = threadIdx.x;
  float s1 = 0.f, s2 = 0.f;
  for (int i = tid; i < N_ROWS; i += 1024) {
    s1 += 1.0f - fdec(rowmax[i]);
    s2 += 1.0f - fdec(colmax[i]);
  }
#pragma unroll
  for (int off = 32; off > 0; off >>= 1) {
    s1 += __shfl_down(s1, off, 64);
    s2 += __shfl_down(s2, off, 64);
  }
  __shared__ float r1[16], r2[16];
  if ((tid & 63) == 0) {
    r1[tid >> 6] = s1;
    r2[tid >> 6] = s2;
  }
  __syncthreads();
  if (tid == 0) {
    const double SIGMA = 0.3;
    const double H_CONST = 0.5 * log(2.0 * 3.14159265358979323846 * SIGMA * SIGMA) + 0.5;
    const float HS = (float)(H_CONST / SIGMA);
    float a1 = 0.f, a2 = 0.f;
#pragma unroll
    for (int w = 0; w < 16; ++w) {
      a1 += r1[w];
      a2 += r2[w];
    }
    out[0] = HS * a1;
    out[1] = HS * a2;
  }
}

extern "C" void kernel_launch(void* const* d_in, const int* in_sizes, int n_in,
                              void* d_out, int out_size, void* d_ws, size_t ws_size,
                              hipStream_t stream) {
  const float* ex = (const float*)d_in[0];
  const float* ey = (const float*)d_in[1];
  float* out = (float*)d_out;
  char* ws = (char*)d_ws;

  unsigned char* exn = (unsigned char*)ws;                                   // 8 MB
  unsigned char* eyn = (unsigned char*)(ws + (size_t)N_ROWS * KDIM);         // 8 MB
  int* rowmax = (int*)(ws + (size_t)N_ROWS * KDIM * 2);                      // 32 KB
  int* colmax = rowmax + N_ROWS;                                             // 32 KB

  normalize_kernel<<<2 * N_ROWS, 256, 0, stream>>>(ex, ey, exn, eyn, rowmax, colmax);
  gemm_max_kernel<<<dim3(64, 64), 256, 0, stream>>>(exn, eyn, rowmax, colmax);
  finalize_kernel<<<1, 1024, 0, stream>>>(rowmax, colmax, out);
}